// Round 10
// baseline (83.507 us; speedup 1.0000x reference)
//
#include <hip/hip_runtime.h>
#include <math.h>

#define BS   16
#define PP   2048
#define CIN  500
#define NROW (BS * PP)            // 32768
#define NIG  256                  // i-groups per batch (8 i each)
#define NBLK_IOU (BS * NIG)       // 4096
#define NBT2 128
#define HIMASK 0xFFFFF800u

typedef int v8i __attribute__((ext_vector_type(8)));

// ---------------------------------------------------------------------------
// K1: xr_k = softmax(inputs @ fc_w^T + fc_b); 4 rows per wave, 16 per block.
// ---------------------------------------------------------------------------
__global__ void __launch_bounds__(256) fc_softmax_kernel(
    const float* __restrict__ inputs, const float* __restrict__ fc_w,
    const float* __restrict__ fc_b, float* __restrict__ out)
{
    __shared__ float4 wL[CIN];
    int tid = threadIdx.x;
    for (int k = tid; k < CIN; k += 256)
        wL[k] = make_float4(fc_w[k], fc_w[CIN + k], fc_w[2 * CIN + k], fc_w[3 * CIN + k]);
    __syncthreads();

    int lane = tid & 63;
    int wv   = tid >> 6;
#pragma unroll
    for (int r = 0; r < 4; ++r) {
        int row = blockIdx.x * 16 + wv * 4 + r;
        const float4* in4 = (const float4*)(inputs + (size_t)row * CIN);
        float a0 = 0.f, a1 = 0.f, a2 = 0.f, a3 = 0.f;
#pragma unroll
        for (int t = 0; t < 2; ++t) {
            int f = t * 64 + lane;          // 125 float4 per row
            if (f < 125) {
                float4 x = in4[f];
                float4 w0 = wL[f * 4 + 0], w1 = wL[f * 4 + 1];
                float4 w2 = wL[f * 4 + 2], w3 = wL[f * 4 + 3];
                a0 += x.x * w0.x + x.y * w1.x + x.z * w2.x + x.w * w3.x;
                a1 += x.x * w0.y + x.y * w1.y + x.z * w2.y + x.w * w3.y;
                a2 += x.x * w0.z + x.y * w1.z + x.z * w2.z + x.w * w3.z;
                a3 += x.x * w0.w + x.y * w1.w + x.z * w2.w + x.w * w3.w;
            }
        }
#pragma unroll
        for (int off = 32; off > 0; off >>= 1) {
            a0 += __shfl_xor(a0, off);
            a1 += __shfl_xor(a1, off);
            a2 += __shfl_xor(a2, off);
            a3 += __shfl_xor(a3, off);
        }
        if (lane == 0) {
            a0 += fc_b[0]; a1 += fc_b[1]; a2 += fc_b[2]; a3 += fc_b[3];
            float m = fmaxf(fmaxf(a0, a1), fmaxf(a2, a3));
            float e0 = expf(a0 - m), e1 = expf(a1 - m), e2 = expf(a2 - m), e3 = expf(a3 - m);
            float inv = 1.0f / (e0 + e1 + e2 + e3);
            ((float4*)out)[row] = make_float4(e0 * inv, e1 * inv, e2 * inv, e3 * inv);
        }
    }
}

// ---------------------------------------------------------------------------
// K2: prep — one block per (b, c): candidate logic (score>0.5, fallback to
// first-argmax one-hot when count<=1); writes mask dword into the 32-B per-j
// record {x1,y1,x2,y2,area,m0,m1,m2}. c==0 blocks also write box+area.
// ---------------------------------------------------------------------------
__global__ void __launch_bounds__(256) prep_kernel(
    const float* __restrict__ pre_score, const float* __restrict__ rois,
    unsigned* __restrict__ rec2d)
{
    int bc = blockIdx.x;          // b*3 + c
    int b = bc / 3, c = bc - b * 3;
    int tid = threadIdx.x;
    __shared__ float sv[256];
    __shared__ int   si[256];
    __shared__ int   sn[256];

    float v[8];
#pragma unroll
    for (int t = 0; t < 8; ++t) {
        int j = t * 256 + tid;
        v[t] = pre_score[((size_t)b * PP + j) * 3 + c];
    }
    float bv = -1.0f; int bi = 0; int cnt = 0;
#pragma unroll
    for (int t = 0; t < 8; ++t) {
        int j = t * 256 + tid;
        if (v[t] > 0.5f) cnt++;
        if (v[t] > bv) { bv = v[t]; bi = j; }   // strict > => first max
    }
    sv[tid] = bv; si[tid] = bi; sn[tid] = cnt;
    __syncthreads();
    for (int s2 = 128; s2 > 0; s2 >>= 1) {
        if (tid < s2) {
            float ov = sv[tid + s2]; int oi = si[tid + s2];
            if (ov > sv[tid] || (ov == sv[tid] && oi < si[tid])) { sv[tid] = ov; si[tid] = oi; }
            sn[tid] += sn[tid + s2];
        }
        __syncthreads();
    }
    int total = sn[0];
    int amax  = si[0];
#pragma unroll
    for (int t = 0; t < 8; ++t) {
        int j = t * 256 + tid;
        bool cb = (total <= 1) ? (j == amax) : (v[t] > 0.5f);
        rec2d[((size_t)b * PP + j) * 8 + 5 + c] = cb ? 0xFFFFFFFFu : 0u;
    }
    if (c == 0) {
        const float4* rb = (const float4*)(rois + (size_t)b * PP * 4);
#pragma unroll
        for (int t = 0; t < 8; ++t) {
            int j = t * 256 + tid;
            float4 bx = rb[j];
            float area = (bx.z - bx.x) * (bx.w - bx.y);
            unsigned* r = rec2d + ((size_t)b * PP + j) * 8;
            r[0] = __float_as_uint(bx.x);
            r[1] = __float_as_uint(bx.y);
            r[2] = __float_as_uint(bx.z);
            r[3] = __float_as_uint(bx.w);
            r[4] = __float_as_uint(area);
        }
    }
}

// ---------------------------------------------------------------------------
// K3: iou — block = 256 thr (4 waves) covers 8 i's (SGPR, loaded once) x all
// 2048 j's (per-lane, coalesced dwordx4 loads, compiler-pipelined vmcnt).
// Packed-key argmax (key = iou_hi_bits | (2047-j)), wave shfl-reduce + tiny
// LDS merge -> FINAL per-(b,i,c) keys. No merge kernel needed.
// ---------------------------------------------------------------------------
__global__ void __launch_bounds__(256) iou_kernel(
    const unsigned* __restrict__ rec2d, unsigned* __restrict__ keys)
{
    __shared__ unsigned red[4][24];
    int bid = blockIdx.x;
    int ig  = bid & (NIG - 1);
    int b   = bid >> 8;
    int tid = threadIdx.x, lane = tid & 63, w = tid >> 6;

    unsigned long long ibase = (unsigned long long)rec2d
                             + ((size_t)b * PP + ig * 8) * 32;
    v8i ir0, ir1, ir2, ir3, ir4, ir5, ir6, ir7;
    asm volatile("s_load_dwordx8 %0, %1, 0x0"  : "=s"(ir0) : "s"(ibase));
    asm volatile("s_load_dwordx8 %0, %1, 0x20" : "=s"(ir1) : "s"(ibase));
    asm volatile("s_load_dwordx8 %0, %1, 0x40" : "=s"(ir2) : "s"(ibase));
    asm volatile("s_load_dwordx8 %0, %1, 0x60" : "=s"(ir3) : "s"(ibase));
    asm volatile("s_load_dwordx8 %0, %1, 0x80" : "=s"(ir4) : "s"(ibase));
    asm volatile("s_load_dwordx8 %0, %1, 0xa0" : "=s"(ir5) : "s"(ibase));
    asm volatile("s_load_dwordx8 %0, %1, 0xc0" : "=s"(ir6) : "s"(ibase));
    asm volatile("s_load_dwordx8 %0, %1, 0xe0" : "=s"(ir7) : "s"(ibase));
    asm volatile("s_waitcnt lgkmcnt(0)"
                 : "+s"(ir0), "+s"(ir1), "+s"(ir2), "+s"(ir3),
                   "+s"(ir4), "+s"(ir5), "+s"(ir6), "+s"(ir7));

    unsigned best[8][3];
#pragma unroll
    for (int s = 0; s < 8; ++s) { best[s][0] = 0u; best[s][1] = 0u; best[s][2] = 0u; }

    const uint4* jrec = (const uint4*)rec2d + (size_t)b * PP * 2;

#pragma unroll 4
    for (int k = 0; k < 8; ++k) {
        int j = k * 256 + tid;
        uint4 lo = jrec[2 * j];
        uint4 hi = jrec[2 * j + 1];
        float bjx = __uint_as_float(lo.x), bjy = __uint_as_float(lo.y);
        float bjz = __uint_as_float(lo.z), bjw = __uint_as_float(lo.w);
        float aj  = __uint_as_float(hi.x);
        unsigned jf = (unsigned)(2047 - j);

#define ONE_SLOT(IR, S)                                                        \
        {                                                                      \
            float lx = fmaxf(__uint_as_float((unsigned)IR[0]), bjx);           \
            float ly = fmaxf(__uint_as_float((unsigned)IR[1]), bjy);           \
            float rx = fminf(__uint_as_float((unsigned)IR[2]), bjz);           \
            float ry = fminf(__uint_as_float((unsigned)IR[3]), bjw);           \
            float ww = fmaxf(rx - lx, 0.f), h2 = fmaxf(ry - ly, 0.f);          \
            float inter = ww * h2;                                             \
            float uni   = (__uint_as_float((unsigned)IR[4]) + aj) - inter;     \
            float iou   = inter * __builtin_amdgcn_rcpf(uni);                  \
            unsigned pk = (__float_as_uint(iou) & HIMASK) | jf;                \
            unsigned k0 = pk & hi.y, k1 = pk & hi.z, k2 = pk & hi.w;           \
            best[S][0] = best[S][0] > k0 ? best[S][0] : k0;                    \
            best[S][1] = best[S][1] > k1 ? best[S][1] : k1;                    \
            best[S][2] = best[S][2] > k2 ? best[S][2] : k2;                    \
        }
        ONE_SLOT(ir0, 0) ONE_SLOT(ir1, 1) ONE_SLOT(ir2, 2) ONE_SLOT(ir3, 3)
        ONE_SLOT(ir4, 4) ONE_SLOT(ir5, 5) ONE_SLOT(ir6, 6) ONE_SLOT(ir7, 7)
#undef ONE_SLOT
    }

    // wave-level max-reduce of 24 packed keys, then 4-wave LDS merge
#pragma unroll
    for (int s = 0; s < 8; ++s) {
#pragma unroll
        for (int c = 0; c < 3; ++c) {
            unsigned vv = best[s][c];
#pragma unroll
            for (int off = 32; off > 0; off >>= 1) {
                unsigned o = (unsigned)__shfl_xor((int)vv, off);
                vv = vv > o ? vv : o;
            }
            if (lane == 0) red[w][s * 3 + c] = vv;
        }
    }
    __syncthreads();
    if (tid < 24) {
        unsigned vv = red[0][tid];
        unsigned o1 = red[1][tid], o2 = red[2][tid], o3 = red[3][tid];
        vv = vv > o1 ? vv : o1;
        vv = vv > o2 ? vv : o2;
        vv = vv > o3 ? vv : o3;
        int s = tid / 3, c = tid - s * 3;
        keys[((size_t)b * 3 + c) * PP + ig * 8 + s] = vv;
    }
}

// ---------------------------------------------------------------------------
// K4: per-i sequential class logic + focal loss; per-block partial sums.
// 128 blocks x 256 threads.
// ---------------------------------------------------------------------------
__global__ void __launch_bounds__(256) focal_kernel(
    const unsigned* __restrict__ keys, const float* __restrict__ pre_score,
    const int* __restrict__ labels, const float* __restrict__ xr,
    float* __restrict__ partials)
{
    __shared__ float redw[4], redf[4];
    int bt = blockIdx.x;
    int b = bt >> 3, it = bt & 7;
    int tid = threadIdx.x;
    int i = it * 256 + tid;

    float I = 0.f, wv = 0.f;
    int target = 3;
#pragma unroll
    for (int c = 0; c < 3; ++c) {
        unsigned k = keys[((size_t)b * 3 + c) * PP + i];
        int   jv    = 2047 - (int)(k & 2047u);
        float bestv = __uint_as_float(k & HIMASK);
        bestv = (labels[b * 3 + c] != 0) ? bestv : -1.0f;
        if (bestv > I) {
            wv = pre_score[((size_t)b * PP + jv) * 3 + c];
            if (bestv > 0.5f && target == 3) target = c;
            I = bestv;
        }
    }
    // focal loss on double-softmaxed scores
    int gi = b * PP + i;
    float4 x4 = ((const float4*)xr)[gi];
    float m = fmaxf(fmaxf(x4.x, x4.y), fmaxf(x4.z, x4.w));
    float e0 = expf(x4.x - m), e1 = expf(x4.y - m), e2 = expf(x4.z - m), e3 = expf(x4.w - m);
    float ssum = e0 + e1 + e2 + e3;
    float et = (target == 0) ? e0 : (target == 1) ? e1 : (target == 2) ? e2 : e3;
    float pt = et / ssum;
    pt = fminf(fmaxf(pt, 1e-7f), 1.0f - 1e-7f);
    float fl = -logf(pt) * (1.0f - pt) * (1.0f - pt);

    float sw = wv, sf = fl;
#pragma unroll
    for (int off = 32; off > 0; off >>= 1) {
        sw += __shfl_down(sw, off);
        sf += __shfl_down(sf, off);
    }
    if ((tid & 63) == 0) { redw[tid >> 6] = sw; redf[tid >> 6] = sf; }
    __syncthreads();
    if (tid == 0) {
        partials[bt * 2 + 0] = redw[0] + redw[1] + redw[2] + redw[3];
        partials[bt * 2 + 1] = redf[0] + redf[1] + redf[2] + redf[3];
    }
}

// ---------------------------------------------------------------------------
// K5: deterministic finalize: loss = mean(w) * mean(floss)
// ---------------------------------------------------------------------------
__global__ void __launch_bounds__(256) finalize_kernel(
    const float* __restrict__ partials, float* __restrict__ out_loss)
{
    __shared__ float swL[256], sfL[256];
    int tid = threadIdx.x;
    float sw = (tid < NBT2) ? partials[2 * tid] : 0.f;
    float sf = (tid < NBT2) ? partials[2 * tid + 1] : 0.f;
    swL[tid] = sw; sfL[tid] = sf;
    __syncthreads();
    for (int s = 128; s > 0; s >>= 1) {
        if (tid < s) { swL[tid] += swL[tid + s]; sfL[tid] += sfL[tid + s]; }
        __syncthreads();
    }
    if (tid == 0)
        out_loss[0] = (swL[0] / (float)NROW) * (sfL[0] / (float)NROW);
}

// ---------------------------------------------------------------------------
extern "C" void kernel_launch(void* const* d_in, const int* in_sizes, int n_in,
                              void* d_out, int out_size, void* d_ws, size_t ws_size,
                              hipStream_t stream)
{
    const float* inputs    = (const float*)d_in[0];
    const float* pre_score = (const float*)d_in[1];
    const int*   labels    = (const int*)d_in[2];
    const float* rois      = (const float*)d_in[3];
    // d_in[4] = num (2048, fixed)
    const float* fc_w      = (const float*)d_in[5];
    const float* fc_b      = (const float*)d_in[6];

    float* out = (float*)d_out;
    char* ws = (char*)d_ws;
    unsigned* keys     = (unsigned*)ws;                    // 384 KiB
    unsigned* rec2d    = (unsigned*)(ws + 393216);         // 1 MiB
    float*    partials = (float*)(ws + 393216 + 1048576);  // 1 KiB

    prep_kernel<<<BS * 3, 256, 0, stream>>>(pre_score, rois, rec2d);
    fc_softmax_kernel<<<NROW / 16, 256, 0, stream>>>(inputs, fc_w, fc_b, out);
    iou_kernel<<<NBLK_IOU, 256, 0, stream>>>(rec2d, keys);
    focal_kernel<<<NBT2, 256, 0, stream>>>(keys, pre_score, labels, out, partials);
    finalize_kernel<<<1, 256, 0, stream>>>(partials, out + (size_t)NROW * 4);
}

// Round 13
// 62.291 us; speedup vs baseline: 1.3406x; 1.3406x over previous
//
#include <hip/hip_runtime.h>
#include <math.h>

#define BS   16
#define PP   2048
#define CIN  500
#define NROW (BS * PP)            // 32768
#define JQ   256                  // j's per iou block
#define NQ   8                    // j slices
#define IT   256                  // i's per iou block (4 slots/lane)
#define NIT  8                    // i tiles per batch
#define NBLK_IOU (BS * NIT * NQ)  // 1024
#define NBT2 128
#define HIMASK 0xFFFFF800u

typedef int v8i __attribute__((ext_vector_type(8)));

// ---------------------------------------------------------------------------
// K1: prep — candidate logic (score>0.5, fallback to first-argmax one-hot
// when count<=1). Writes 32-B record per j: {x1,y1,x2,y2,area,m0,m1,m2},
// m_c = cand ? 0xFFFFFFFF : 0. Record is s_load_dwordx8-able.
// ---------------------------------------------------------------------------
__global__ void __launch_bounds__(256) prep_kernel(
    const float* __restrict__ pre_score, const float* __restrict__ rois,
    uint4* __restrict__ rec2)
{
    int b = blockIdx.x;
    int tid = threadIdx.x;
    __shared__ float sv[256];
    __shared__ int   si[256];
    __shared__ int   sc[256];

    float v0[8], v1[8], v2[8];
    unsigned char bits[8];
#pragma unroll
    for (int t = 0; t < 8; ++t) {
        int j = t * 256 + tid;
        const float* p = pre_score + ((size_t)b * PP + j) * 3;
        v0[t] = p[0]; v1[t] = p[1]; v2[t] = p[2];
        bits[t] = 0;
    }

#define PREP_CLASS(VV, CBIT)                                                   \
    {                                                                          \
        float bv = -1.0f; int bi = 0; int cnt = 0;                             \
        _Pragma("unroll")                                                      \
        for (int t = 0; t < 8; ++t) {                                          \
            int j = t * 256 + tid;                                             \
            float v = VV[t];                                                   \
            if (v > 0.5f) cnt++;                                               \
            if (v > bv) { bv = v; bi = j; }                                    \
        }                                                                      \
        sv[tid] = bv; si[tid] = bi; sc[tid] = cnt;                             \
        __syncthreads();                                                       \
        for (int s2 = 128; s2 > 0; s2 >>= 1) {                                 \
            if (tid < s2) {                                                    \
                float ov = sv[tid + s2]; int oi = si[tid + s2];                \
                if (ov > sv[tid] || (ov == sv[tid] && oi < si[tid])) {         \
                    sv[tid] = ov; si[tid] = oi;                                \
                }                                                              \
                sc[tid] += sc[tid + s2];                                       \
            }                                                                  \
            __syncthreads();                                                   \
        }                                                                      \
        int total = sc[0];                                                     \
        int amax  = si[0];                                                     \
        __syncthreads();                                                       \
        _Pragma("unroll")                                                      \
        for (int t = 0; t < 8; ++t) {                                          \
            int j = t * 256 + tid;                                             \
            bool cb = (total <= 1) ? (j == amax) : (VV[t] > 0.5f);             \
            if (cb) bits[t] |= (unsigned char)(CBIT);                          \
        }                                                                      \
    }

    PREP_CLASS(v0, 1)
    PREP_CLASS(v1, 2)
    PREP_CLASS(v2, 4)
#undef PREP_CLASS

    const float4* rb = (const float4*)(rois + (size_t)b * PP * 4);
#pragma unroll
    for (int t = 0; t < 8; ++t) {
        int j = t * 256 + tid;
        float4 bx = rb[j];
        float area = (bx.z - bx.x) * (bx.w - bx.y);
        uint4 lo, hi;
        lo.x = __float_as_uint(bx.x);
        lo.y = __float_as_uint(bx.y);
        lo.z = __float_as_uint(bx.z);
        lo.w = __float_as_uint(bx.w);
        hi.x = __float_as_uint(area);
        hi.y = (bits[t] & 1) ? 0xFFFFFFFFu : 0u;
        hi.z = (bits[t] & 2) ? 0xFFFFFFFFu : 0u;
        hi.w = (bits[t] & 4) ? 0xFFFFFFFFu : 0u;
        rec2[((size_t)b * PP + j) * 2 + 0] = lo;
        rec2[((size_t)b * PP + j) * 2 + 1] = hi;
    }
}

// ---------------------------------------------------------------------------
// K2: fused iou + fc_softmax. 512 thr (8 waves) cover 256 i's (4 slots/lane)
// x 256 j's (SMEM s_load_dwordx8 broadcast, double-buffered batches of 4).
// Packed-key argmax (key = (iou & HIMASK) | (2047-j)) — exact first-max
// tie-break. Tail: each block computes 32 rows of xr = softmax(inputs@W^T+b);
// the tail's VMEM streaming overlaps other blocks' VALU-bound j-loops on the
// same CU, hiding fc's HBM time inside the iou compute.
// ---------------------------------------------------------------------------
__global__ void __launch_bounds__(512) fused_kernel(
    const float* __restrict__ rois, const unsigned* __restrict__ rec2d,
    unsigned* __restrict__ qres,
    const float* __restrict__ inputs, const float* __restrict__ fc_w,
    const float* __restrict__ fc_b, float* __restrict__ out)
{
    __shared__ unsigned bestA[3][8][IT];  // 24 KiB
    __shared__ float4   wLf[CIN];         // 8 KiB
    int bid = blockIdx.x;
    int q   = bid & 7;
    int it  = (bid >> 3) & 7;
    int b   = bid >> 6;
    int tid = threadIdx.x, lane = tid & 63;
    int w   = __builtin_amdgcn_readfirstlane(tid >> 6);   // wave-uniform -> SGPR

    // stage fc weights (read in tail; ordered by the post-loop barrier)
    for (int k2 = tid; k2 < CIN; k2 += 512)
        wLf[k2] = make_float4(fc_w[k2], fc_w[CIN + k2],
                              fc_w[2 * CIN + k2], fc_w[3 * CIN + k2]);

    const float4* rbase = (const float4*)(rois + (size_t)b * PP * 4);
    float4 bx[4];
    float  ax[4];
#pragma unroll
    for (int s = 0; s < 4; ++s) {
        bx[s] = rbase[it * IT + s * 64 + lane];
        ax[s] = (bx[s].z - bx[s].x) * (bx[s].w - bx[s].y);
    }

    int jb  = q * JQ + w * 32;                     // uniform
    int jfb = 2047 - jb;                           // uniform
    unsigned long long addr = (unsigned long long)rec2d
                            + (unsigned long long)(b * PP + jb) * 32ull;

    unsigned best[4][3];
#pragma unroll
    for (int s = 0; s < 4; ++s) { best[s][0] = 0u; best[s][1] = 0u; best[s][2] = 0u; }

    v8i A0, A1, A2, A3, B0, B1, B2, B3;

#define ISSUE4(R0, R1, R2, R3)                                                 \
    asm volatile("s_load_dwordx8 %0, %1, 0x0"  : "=&s"(R0) : "s"(addr));       \
    asm volatile("s_load_dwordx8 %0, %1, 0x20" : "=&s"(R1) : "s"(addr));       \
    asm volatile("s_load_dwordx8 %0, %1, 0x40" : "=&s"(R2) : "s"(addr));       \
    asm volatile("s_load_dwordx8 %0, %1, 0x60" : "=&s"(R3) : "s"(addr));       \
    addr += 128;

#define DO_J(R, KOFF)                                                          \
    {                                                                          \
        float bjx = __uint_as_float((unsigned)R[0]);                           \
        float bjy = __uint_as_float((unsigned)R[1]);                           \
        float bjz = __uint_as_float((unsigned)R[2]);                           \
        float bjw = __uint_as_float((unsigned)R[3]);                           \
        float aj  = __uint_as_float((unsigned)R[4]);                           \
        unsigned m0 = (unsigned)R[5], m1 = (unsigned)R[6], m2 = (unsigned)R[7];\
        unsigned jf = (unsigned)(jfb - (KOFF));                                \
        _Pragma("unroll")                                                      \
        for (int s = 0; s < 4; ++s) {                                          \
            float lx = fmaxf(bx[s].x, bjx), ly = fmaxf(bx[s].y, bjy);          \
            float rx = fminf(bx[s].z, bjz), ry = fminf(bx[s].w, bjw);          \
            float ww = fmaxf(rx - lx, 0.f), hh = fmaxf(ry - ly, 0.f);          \
            float inter = ww * hh;                                             \
            float uni   = (ax[s] + aj) - inter;                                \
            float iou   = inter * __builtin_amdgcn_rcpf(uni);                  \
            unsigned pk = (__float_as_uint(iou) & HIMASK) | jf;                \
            unsigned k0 = pk & m0, k1 = pk & m1, k2 = pk & m2;                 \
            best[s][0] = best[s][0] > k0 ? best[s][0] : k0;                    \
            best[s][1] = best[s][1] > k1 ? best[s][1] : k1;                    \
            best[s][2] = best[s][2] > k2 ? best[s][2] : k2;                    \
        }                                                                      \
    }

#define BATCH(C0, C1, C2, C3, N0, N1, N2, N3, BASE, DOISSUE)                   \
    asm volatile("s_waitcnt lgkmcnt(0)"                                        \
                 : "+s"(C0), "+s"(C1), "+s"(C2), "+s"(C3));                    \
    __builtin_amdgcn_sched_barrier(0);                                         \
    if (DOISSUE) { ISSUE4(N0, N1, N2, N3) }                                    \
    DO_J(C0, (BASE) + 0) DO_J(C1, (BASE) + 1)                                  \
    DO_J(C2, (BASE) + 2) DO_J(C3, (BASE) + 3)

    ISSUE4(A0, A1, A2, A3)
    BATCH(A0, A1, A2, A3, B0, B1, B2, B3,  0, 1)
    BATCH(B0, B1, B2, B3, A0, A1, A2, A3,  4, 1)
    BATCH(A0, A1, A2, A3, B0, B1, B2, B3,  8, 1)
    BATCH(B0, B1, B2, B3, A0, A1, A2, A3, 12, 1)
    BATCH(A0, A1, A2, A3, B0, B1, B2, B3, 16, 1)
    BATCH(B0, B1, B2, B3, A0, A1, A2, A3, 20, 1)
    BATCH(A0, A1, A2, A3, B0, B1, B2, B3, 24, 1)
    BATCH(B0, B1, B2, B3, A0, A1, A2, A3, 28, 0)

#undef BATCH
#undef DO_J
#undef ISSUE4

#pragma unroll
    for (int s = 0; s < 4; ++s) {
        bestA[0][w][s * 64 + lane] = best[s][0];
        bestA[1][w][s * 64 + lane] = best[s][1];
        bestA[2][w][s * 64 + lane] = best[s][2];
    }
    __syncthreads();

    if (tid < IT) {
#pragma unroll
        for (int c = 0; c < 3; ++c) {
            unsigned m = bestA[c][0][tid];
#pragma unroll
            for (int w2 = 1; w2 < 8; ++w2) {
                unsigned o = bestA[c][w2][tid];
                m = m > o ? m : o;
            }
            qres[(((size_t)b * NQ + q) * 3 + c) * PP + it * IT + tid] = m;
        }
    }

    // ---- fc softmax tail: rows [bid*32, bid*32+32), 4 per wave ----
#pragma unroll
    for (int r = 0; r < 4; ++r) {
        int row = bid * 32 + w * 4 + r;
        const float4* in4 = (const float4*)(inputs + (size_t)row * CIN);
        float a0 = 0.f, a1 = 0.f, a2 = 0.f, a3 = 0.f;
#pragma unroll
        for (int t = 0; t < 2; ++t) {
            int f = t * 64 + lane;          // 125 float4 per row
            if (f < 125) {
                float4 x = in4[f];
                float4 w0 = wLf[f * 4 + 0], w1 = wLf[f * 4 + 1];
                float4 w2 = wLf[f * 4 + 2], w3 = wLf[f * 4 + 3];
                a0 += x.x * w0.x + x.y * w1.x + x.z * w2.x + x.w * w3.x;
                a1 += x.x * w0.y + x.y * w1.y + x.z * w2.y + x.w * w3.y;
                a2 += x.x * w0.z + x.y * w1.z + x.z * w2.z + x.w * w3.z;
                a3 += x.x * w0.w + x.y * w1.w + x.z * w2.w + x.w * w3.w;
            }
        }
#pragma unroll
        for (int off = 32; off > 0; off >>= 1) {
            a0 += __shfl_xor(a0, off);
            a1 += __shfl_xor(a1, off);
            a2 += __shfl_xor(a2, off);
            a3 += __shfl_xor(a3, off);
        }
        if (lane == 0) {
            a0 += fc_b[0]; a1 += fc_b[1]; a2 += fc_b[2]; a3 += fc_b[3];
            float m = fmaxf(fmaxf(a0, a1), fmaxf(a2, a3));
            float e0 = expf(a0 - m), e1 = expf(a1 - m);
            float e2 = expf(a2 - m), e3 = expf(a3 - m);
            float inv = 1.0f / (e0 + e1 + e2 + e3);
            ((float4*)out)[row] = make_float4(e0 * inv, e1 * inv, e2 * inv, e3 * inv);
        }
    }
}

// ---------------------------------------------------------------------------
// K3: merge j-slices + sequential class logic + focal loss; per-(b,it)
// partial sums. 128 blocks x 256 threads.
// ---------------------------------------------------------------------------
__global__ void __launch_bounds__(256) merge_focal_kernel(
    const unsigned* __restrict__ qres, const float* __restrict__ pre_score,
    const int* __restrict__ labels, const float* __restrict__ xr,
    float* __restrict__ partials)
{
    __shared__ float redw[4], redf[4];
    int bt = blockIdx.x;
    int b = bt >> 3, it = bt & 7;
    int tid = threadIdx.x;
    int i = it * IT + tid;

    float I = 0.f, wv = 0.f;
    int target = 3;
#pragma unroll
    for (int c = 0; c < 3; ++c) {
        unsigned k = 0u;
#pragma unroll
        for (int qq = 0; qq < NQ; ++qq) {
            unsigned h = qres[(((size_t)b * NQ + qq) * 3 + c) * PP + i];
            k = k > h ? k : h;   // packed keys globally unique per j
        }
        int   jv    = 2047 - (int)(k & 2047u);
        float bestv = __uint_as_float(k & HIMASK);
        bestv = (labels[b * 3 + c] != 0) ? bestv : -1.0f;
        if (bestv > I) {
            wv = pre_score[((size_t)b * PP + jv) * 3 + c];
            if (bestv > 0.5f && target == 3) target = c;
            I = bestv;
        }
    }
    // focal loss on double-softmaxed scores
    int gi = b * PP + i;
    float4 x4 = ((const float4*)xr)[gi];
    float m = fmaxf(fmaxf(x4.x, x4.y), fmaxf(x4.z, x4.w));
    float e0 = expf(x4.x - m), e1 = expf(x4.y - m), e2 = expf(x4.z - m), e3 = expf(x4.w - m);
    float ssum = e0 + e1 + e2 + e3;
    float et = (target == 0) ? e0 : (target == 1) ? e1 : (target == 2) ? e2 : e3;
    float pt = et / ssum;
    pt = fminf(fmaxf(pt, 1e-7f), 1.0f - 1e-7f);
    float fl = -logf(pt) * (1.0f - pt) * (1.0f - pt);

    float sw = wv, sf = fl;
#pragma unroll
    for (int off = 32; off > 0; off >>= 1) {
        sw += __shfl_down(sw, off);
        sf += __shfl_down(sf, off);
    }
    if ((tid & 63) == 0) { redw[tid >> 6] = sw; redf[tid >> 6] = sf; }
    __syncthreads();
    if (tid == 0) {
        partials[bt * 2 + 0] = redw[0] + redw[1] + redw[2] + redw[3];
        partials[bt * 2 + 1] = redf[0] + redf[1] + redf[2] + redf[3];
    }
}

// ---------------------------------------------------------------------------
// K4: deterministic finalize: loss = mean(w) * mean(floss)
// ---------------------------------------------------------------------------
__global__ void __launch_bounds__(256) finalize_kernel(
    const float* __restrict__ partials, float* __restrict__ out_loss)
{
    __shared__ float swL[256], sfL[256];
    int tid = threadIdx.x;
    float sw = (tid < NBT2) ? partials[2 * tid] : 0.f;
    float sf = (tid < NBT2) ? partials[2 * tid + 1] : 0.f;
    swL[tid] = sw; sfL[tid] = sf;
    __syncthreads();
    for (int s = 128; s > 0; s >>= 1) {
        if (tid < s) { swL[tid] += swL[tid + s]; sfL[tid] += sfL[tid + s]; }
        __syncthreads();
    }
    if (tid == 0)
        out_loss[0] = (swL[0] / (float)NROW) * (sfL[0] / (float)NROW);
}

// ---------------------------------------------------------------------------
extern "C" void kernel_launch(void* const* d_in, const int* in_sizes, int n_in,
                              void* d_out, int out_size, void* d_ws, size_t ws_size,
                              hipStream_t stream)
{
    const float* inputs    = (const float*)d_in[0];
    const float* pre_score = (const float*)d_in[1];
    const int*   labels    = (const int*)d_in[2];
    const float* rois      = (const float*)d_in[3];
    // d_in[4] = num (2048, fixed)
    const float* fc_w      = (const float*)d_in[5];
    const float* fc_b      = (const float*)d_in[6];

    float* out = (float*)d_out;
    char* ws = (char*)d_ws;
    unsigned* qres     = (unsigned*)ws;                    // 3.0 MiB
    uint4*    rec2     = (uint4*)(ws + 3145728);           // 1.0 MiB
    float*    partials = (float*)(ws + 3145728 + 1048576); // 1 KiB

    prep_kernel<<<BS, 256, 0, stream>>>(pre_score, rois, rec2);
    fused_kernel<<<NBLK_IOU, 512, 0, stream>>>(rois, (const unsigned*)rec2, qres,
                                               inputs, fc_w, fc_b, out);
    merge_focal_kernel<<<NBT2, 256, 0, stream>>>(qres, pre_score, labels, out, partials);
    finalize_kernel<<<1, 256, 0, stream>>>(partials, out + (size_t)NROW * 4);
}